// Round 4
// baseline (307.054 us; speedup 1.0000x reference)
//
#include <hip/hip_runtime.h>
#include <math.h>

#define NN 1024
#define NPIX (NN * NN)
#define NB 16
#define BPB 128                 // blocks per batch
#define NBLK (NB * BPB)         // 2048
#define ROWS 8                  // image rows per block (CHUNK = ROWS*NN = 8192)
#define RADIUS 4.76837158203125e-07f  // 1/N^2/2 = 2^-21, exact in fp32

typedef float f4 __attribute__((ext_vector_type(4)));   // legal for nontemporal builtins

struct Partial {
    float m1, d1; int i1;       // variant 1: masked = hist * sal
    float m2, d2; int i2;       // variant 2: masked = sal (hist forced to ones)
    unsigned flags;             // bit0: any hist!=0 ; bit1: any m1!=0 ; bit2: any m2!=0
    int pad;
};

__device__ __forceinline__ void comp_upd(float om, float od, int oi,
                                         float& bm, float& bd, int& bi) {
    // lexicographic max on (m desc, d asc, idx asc)
    if (om > bm || (om == bm && (od < bd || (od == bd && oi < bi)))) {
        bm = om; bd = od; bi = oi;
    }
}

// ------- Kernel 1: streaming composite reduction + last-block finalize -------
__global__ __launch_bounds__(256) void k_reduce_final(
        const float* __restrict__ sal, const float* __restrict__ hist,
        const float* __restrict__ cur, const float* __restrict__ grid,
        Partial* __restrict__ part, unsigned* __restrict__ cnt,
        float* __restrict__ out_xy, float* __restrict__ params) {
    __shared__ float r[NN];
    __shared__ Partial sp[4];
    __shared__ int sLast;
    __shared__ unsigned sfl[4];
    const int tid = threadIdx.x;
    for (int i = tid; i < NN; i += 256) r[i] = grid[i * 2];  // row 0, ch x == linspace
    const int b   = blockIdx.x >> 7;
    const int blk = blockIdx.x & (BPB - 1);
    const float cx = cur[b * 2 + 0];
    const float cy = cur[b * 2 + 1];
    __syncthreads();

    float hdx2[4];
    #pragma unroll
    for (int j = 0; j < 4; ++j) {
        const float dx = r[tid * 4 + j] - cx;
        hdx2[j] = 0.5f * (dx * dx);
    }
    float hdy2[ROWS];
    #pragma unroll
    for (int it = 0; it < ROWS; ++it) {
        const float dy = r[blk * ROWS + it] - cy;
        hdy2[it] = 0.5f * (dy * dy);
    }

    const size_t base = (size_t)b * NPIX + (size_t)blk * (ROWS * NN) + (size_t)tid * 4;
    float bm1 = -INFINITY, bd1 = INFINITY; int bi1 = 0;
    float bm2 = -INFINITY, bd2 = INFINITY; int bi2 = 0;
    float ah = 0.0f, am1 = 0.0f, am2 = 0.0f;   // max-abs accumulators -> flags

    #pragma unroll
    for (int it = 0; it < ROWS; ++it) {
        const f4 s4 = __builtin_nontemporal_load((const f4*)(sal + base + it * NN));
        const f4 h4 = *(const f4*)(hist + base + it * NN);   // keep cached for k_apply
        const int p0 = blk * (ROWS * NN) + it * NN + tid * 4;
        #pragma unroll
        for (int j = 0; j < 4; ++j) {
            const float sv = s4[j];
            const float hv = h4[j];
            const float cd = hdx2[j] + hdy2[it];   // == cur_dist == d
            const float salv = (cd <= RADIUS) ? 0.0f : sv;
            const float m1v = hv * salv;
            ah  = fmaxf(ah,  fabsf(hv));
            am1 = fmaxf(am1, fabsf(m1v));
            am2 = fmaxf(am2, fabsf(salv));
            // ascending p within thread -> strict compares keep first index
            if (m1v > bm1 || (m1v == bm1 && cd < bd1)) { bm1 = m1v; bd1 = cd; bi1 = p0 + j; }
            if (salv > bm2 || (salv == bm2 && cd < bd2)) { bm2 = salv; bd2 = cd; bi2 = p0 + j; }
        }
    }

    unsigned fl = (ah > 0.0f ? 1u : 0u) | (am1 > 0.0f ? 2u : 0u) | (am2 > 0.0f ? 4u : 0u);

    // wave butterfly reduce (64 lanes)
    #pragma unroll
    for (int s = 32; s; s >>= 1) {
        float om = __shfl_xor(bm1, s); float od = __shfl_xor(bd1, s); int oi = __shfl_xor(bi1, s);
        comp_upd(om, od, oi, bm1, bd1, bi1);
        om = __shfl_xor(bm2, s); od = __shfl_xor(bd2, s); oi = __shfl_xor(bi2, s);
        comp_upd(om, od, oi, bm2, bd2, bi2);
        fl |= __shfl_xor(fl, s);
    }
    const int wave = tid >> 6;
    const int lane = tid & 63;
    if (lane == 0) {
        Partial P; P.m1 = bm1; P.d1 = bd1; P.i1 = bi1;
        P.m2 = bm2; P.d2 = bd2; P.i2 = bi2; P.flags = fl; P.pad = 0;
        sp[wave] = P;
    }
    __syncthreads();
    if (tid == 0) {
        Partial P = sp[0];
        for (int w = 1; w < 4; ++w) {
            const Partial Q = sp[w];
            comp_upd(Q.m1, Q.d1, Q.i1, P.m1, P.d1, P.i1);
            comp_upd(Q.m2, Q.d2, Q.i2, P.m2, P.d2, P.i2);
            P.flags |= Q.flags;
        }
        part[blockIdx.x] = P;
        __threadfence();                       // release part[] (device scope)
        const unsigned old = atomicAdd(cnt, 1u);
        sLast = (old == NBLK - 1) ? 1 : 0;
    }
    __syncthreads();
    if (!sLast) return;

    // ---- last block: finalize (256 threads = 4 waves; wave w does batches w*4..w*4+3) ----
    __threadfence();                           // acquire all part[]
    unsigned f = 0;
    for (int i = tid; i < NBLK; i += 256) f |= part[i].flags;
    #pragma unroll
    for (int s = 32; s; s >>= 1) f |= __shfl_xor(f, s);
    if (lane == 0) sfl[wave] = f;
    __syncthreads();
    const unsigned allf = sfl[0] | sfl[1] | sfl[2] | sfl[3];
    const bool histnz = (allf & 1u) != 0;      // !all(hist == 0)

    for (int bb = 0; bb < 4; ++bb) {
        const int fb = wave * 4 + bb;
        float bm = -INFINITY, bd = INFINITY; int bi = 0x7fffffff;
        unsigned anz = 0;
        #pragma unroll
        for (int k = 0; k < 2; ++k) {
            const Partial Q = part[fb * BPB + k * 64 + lane];
            const float m = histnz ? Q.m1 : Q.m2;
            const float d = histnz ? Q.d1 : Q.d2;
            const int   i = histnz ? Q.i1 : Q.i2;
            anz |= histnz ? (Q.flags & 2u) : (Q.flags & 4u);
            comp_upd(m, d, i, bm, bd, bi);
        }
        #pragma unroll
        for (int s = 32; s; s >>= 1) {
            const float om = __shfl_xor(bm, s);
            const float od = __shfl_xor(bd, s);
            const int   oi = __shfl_xor(bi, s);
            anz |= __shfl_xor(anz, s);
            comp_upd(om, od, oi, bm, bd, bi);
        }
        if (lane == 0) {
            const bool all_zero = (anz == 0u);        // all(masked == 0)
            const int idx = (bm > 0.0f) ? bi : 0;     // no valid pos -> argmin of all-inf = 0
            const int py = idx >> 10;
            const int px = idx & (NN - 1);
            const float lx = 2.0f * ((float)(px + 1) / 1024.0f) - 1.0f;
            const float ly = 2.0f * ((float)(py + 1) / 1024.0f) - 1.0f;
            // sm_value = sal (post cur-mask, pre-hist) at (py, px); replicate phase-A math
            const float fcx = cur[fb * 2 + 0];
            const float fcy = cur[fb * 2 + 1];
            const float dx = r[px] - fcx;
            const float dy = r[py] - fcy;
            const float cd = 0.5f * (dx * dx) + 0.5f * (dy * dy);
            const float sv = sal[(size_t)fb * NPIX + idx];
            const float salv = (cd <= RADIUS) ? 0.0f : sv;
            const float sm = fmaxf(salv, 0.0001f);
            const float eps = 10.0f / sm;
            out_xy[2 * fb + 0] = all_zero ? 1.0f : lx;
            out_xy[2 * fb + 1] = all_zero ? 1.0f : ly;
            params[4 * fb + 0] = lx;                   // rbf uses raw loc, not next_xy
            params[4 * fb + 1] = ly;
            params[4 * fb + 2] = eps;
            params[4 * fb + 3] = histnz ? 0.0f : 1.0f; // 1 -> treat hist as ones
        }
    }
}

// ---------------- Kernel 2: RBF mask + hist update ----------------
__global__ __launch_bounds__(256) void k_apply(
        const float* __restrict__ hist, const float* __restrict__ grid,
        const float* __restrict__ params, float* __restrict__ out_hist,
        float* __restrict__ out_mask) {
    __shared__ float r[NN];
    const int tid = threadIdx.x;
    for (int i = tid; i < NN; i += 256) r[i] = grid[i * 2];
    const int b   = blockIdx.x >> 7;
    const int blk = blockIdx.x & (BPB - 1);
    const float lx  = params[4 * b + 0];
    const float ly  = params[4 * b + 1];
    const float eps = params[4 * b + 2];
    const bool useones = params[4 * b + 3] != 0.0f;
    __syncthreads();

    float hdx2[4];
    #pragma unroll
    for (int j = 0; j < 4; ++j) {
        const float dx = r[tid * 4 + j] - lx;
        hdx2[j] = 0.5f * (dx * dx);
    }

    const size_t base = (size_t)b * NPIX + (size_t)blk * (ROWS * NN) + (size_t)tid * 4;
    #pragma unroll
    for (int it = 0; it < ROWS; ++it) {
        const float dy = r[blk * ROWS + it] - ly;
        const float hdy2 = 0.5f * (dy * dy);
        const f4 h4 = *(const f4*)(hist + base + it * NN);   // L3-hot from phase A
        f4 m4, o4;
        #pragma unroll
        for (int j = 0; j < 4; ++j) {
            const float rbf = hdx2[j] + hdy2;
            const float t = rbf * eps;
            const float mk = __expf(-(t * t));
            const float hv = useones ? 1.0f : h4[j];
            float ho = hv * (1.0f - mk);
            ho = fminf(fmaxf(ho, 0.0f), 1.0f);
            m4[j] = mk;
            o4[j] = ho;
        }
        __builtin_nontemporal_store(m4, (f4*)(out_mask + base + it * NN));
        __builtin_nontemporal_store(o4, (f4*)(out_hist + base + it * NN));
    }
}

extern "C" void kernel_launch(void* const* d_in, const int* in_sizes, int n_in,
                              void* d_out, int out_size, void* d_ws, size_t ws_size,
                              hipStream_t stream) {
    const float* sal  = (const float*)d_in[0];   // (B, N, N)
    const float* hist = (const float*)d_in[1];   // (B, 1, N, N)
    const float* cur  = (const float*)d_in[2];   // (B, 2)
    const float* grid = (const float*)d_in[3];   // (N, N, 2)

    float* out      = (float*)d_out;
    float* out_xy   = out;                       // B*2
    float* out_hist = out + NB * 2;              // B*N*N
    float* out_mask = out_hist + NB * NPIX;      // B*N*N

    Partial*  part   = (Partial*)d_ws;                            // 2048*32 B = 64 KiB
    unsigned* cnt    = (unsigned*)((char*)d_ws + NBLK * sizeof(Partial));
    float*    params = (float*)((char*)d_ws + NBLK * sizeof(Partial) + 256);

    (void)hipMemsetAsync(cnt, 0, sizeof(unsigned), stream);       // arrival counter = 0
    k_reduce_final<<<NBLK, 256, 0, stream>>>(sal, hist, cur, grid, part, cnt, out_xy, params);
    k_apply<<<NBLK, 256, 0, stream>>>(hist, grid, params, out_hist, out_mask);
}

// Round 8
// 254.167 us; speedup vs baseline: 1.2081x; 1.2081x over previous
//
#include <hip/hip_runtime.h>
#include <math.h>

#define NN 1024
#define NPIX (NN * NN)
#define NB 16
#define BPB 128                 // blocks per batch
#define NBLK (NB * BPB)         // 2048
#define ROWS 8                  // image rows per block (CHUNK = ROWS*NN = 8192)
#define RADIUS 4.76837158203125e-07f  // 1/N^2/2 = 2^-21, exact in fp32

typedef float f4 __attribute__((ext_vector_type(4)));   // legal for nontemporal builtins

struct Partial {
    float m1, d1; int i1;       // variant 1: masked = hist * sal
    float m2, d2; int i2;       // variant 2: masked = sal (hist forced to ones)
    unsigned flags;             // bit0: any hist!=0 ; bit1: any m1!=0 ; bit2: any m2!=0
    int pad;
};

__device__ __forceinline__ void comp_upd(float om, float od, int oi,
                                         float& bm, float& bd, int& bi) {
    // lexicographic max on (m desc, d asc, idx asc)
    if (om > bm || (om == bm && (od < bd || (od == bd && oi < bi)))) {
        bm = om; bd = od; bi = oi;
    }
}

// ---------------- Kernel 1: streaming composite reduction ----------------
// All 16 global loads are issued back-to-back before any processing: with
// 16 outstanding 16B loads/wave the block is HBM-throughput-limited, not
// latency-limited. cd = 0.5*dx^2 + 0.5*dy^2 separates into a per-thread
// term (4 values) + per-row uniform term, so no LDS reads in the hot loop.
__global__ __launch_bounds__(256) void k_reduce(
        const float* __restrict__ sal, const float* __restrict__ hist,
        const float* __restrict__ cur, const float* __restrict__ grid,
        Partial* __restrict__ part) {
    __shared__ float r[NN];
    __shared__ Partial sp[4];
    const int tid = threadIdx.x;
    for (int i = tid; i < NN; i += 256) r[i] = grid[i * 2];  // row 0, ch x == linspace
    const int b   = blockIdx.x >> 7;
    const int blk = blockIdx.x & (BPB - 1);
    const float cx = cur[b * 2 + 0];
    const float cy = cur[b * 2 + 1];
    __syncthreads();

    float hdx2[4];
    #pragma unroll
    for (int j = 0; j < 4; ++j) {
        const float dx = r[tid * 4 + j] - cx;
        hdx2[j] = 0.5f * (dx * dx);
    }
    float hdy2[ROWS];
    #pragma unroll
    for (int it = 0; it < ROWS; ++it) {
        const float dy = r[blk * ROWS + it] - cy;
        hdy2[it] = 0.5f * (dy * dy);
    }

    const size_t base = (size_t)b * NPIX + (size_t)blk * (ROWS * NN) + (size_t)tid * 4;

    // ---- issue all 16 loads up front ----
    f4 s4a[ROWS], h4a[ROWS];
    #pragma unroll
    for (int it = 0; it < ROWS; ++it)
        s4a[it] = *(const f4*)(sal + base + it * NN);
    #pragma unroll
    for (int it = 0; it < ROWS; ++it)
        h4a[it] = *(const f4*)(hist + base + it * NN);

    float bm1 = -INFINITY, bd1 = INFINITY; int bi1 = 0;
    float bm2 = -INFINITY, bd2 = INFINITY; int bi2 = 0;
    float ah = 0.0f, am1 = 0.0f, am2 = 0.0f;   // max-abs accumulators -> flags

    #pragma unroll
    for (int it = 0; it < ROWS; ++it) {
        const int p0 = blk * (ROWS * NN) + it * NN + tid * 4;
        #pragma unroll
        for (int j = 0; j < 4; ++j) {
            const float sv = s4a[it][j];
            const float hv = h4a[it][j];
            const float cd = hdx2[j] + hdy2[it];   // == cur_dist == d
            const float salv = (cd <= RADIUS) ? 0.0f : sv;
            const float m1v = hv * salv;
            ah  = fmaxf(ah,  fabsf(hv));
            am1 = fmaxf(am1, fabsf(m1v));
            am2 = fmaxf(am2, fabsf(salv));
            // ascending p within thread -> strict compares keep first index
            if (m1v > bm1 || (m1v == bm1 && cd < bd1)) { bm1 = m1v; bd1 = cd; bi1 = p0 + j; }
            if (salv > bm2 || (salv == bm2 && cd < bd2)) { bm2 = salv; bd2 = cd; bi2 = p0 + j; }
        }
    }

    unsigned fl = (ah > 0.0f ? 1u : 0u) | (am1 > 0.0f ? 2u : 0u) | (am2 > 0.0f ? 4u : 0u);

    // wave butterfly reduce (64 lanes)
    #pragma unroll
    for (int s = 32; s; s >>= 1) {
        float om = __shfl_xor(bm1, s); float od = __shfl_xor(bd1, s); int oi = __shfl_xor(bi1, s);
        comp_upd(om, od, oi, bm1, bd1, bi1);
        om = __shfl_xor(bm2, s); od = __shfl_xor(bd2, s); oi = __shfl_xor(bi2, s);
        comp_upd(om, od, oi, bm2, bd2, bi2);
        fl |= __shfl_xor(fl, s);
    }
    const int wave = tid >> 6;
    const int lane = tid & 63;
    if (lane == 0) {
        Partial P; P.m1 = bm1; P.d1 = bd1; P.i1 = bi1;
        P.m2 = bm2; P.d2 = bd2; P.i2 = bi2; P.flags = fl; P.pad = 0;
        sp[wave] = P;
    }
    __syncthreads();
    if (tid == 0) {
        Partial P = sp[0];
        for (int w = 1; w < 4; ++w) {
            const Partial Q = sp[w];
            comp_upd(Q.m1, Q.d1, Q.i1, P.m1, P.d1, P.i1);
            comp_upd(Q.m2, Q.d2, Q.i2, P.m2, P.d2, P.i2);
            P.flags |= Q.flags;
        }
        part[blockIdx.x] = P;
    }
}

// ---------------- Kernel 2: finalize (1 block, 16 waves = 1 per batch) ----------------
__global__ __launch_bounds__(1024) void k_final(
        const Partial* __restrict__ part, const float* __restrict__ sal,
        const float* __restrict__ cur, const float* __restrict__ grid,
        float* __restrict__ out_xy, float* __restrict__ params) {
    __shared__ unsigned shf[16];
    unsigned f = 0;
    for (int i = threadIdx.x; i < NBLK; i += 1024) f |= part[i].flags;
    #pragma unroll
    for (int s = 32; s; s >>= 1) f |= __shfl_xor(f, s);
    const int wave = threadIdx.x >> 6;
    const int lane = threadIdx.x & 63;
    if (lane == 0) shf[wave] = f;
    __syncthreads();
    unsigned allf = 0;
    #pragma unroll
    for (int w = 0; w < 16; ++w) allf |= shf[w];
    const bool histnz = (allf & 1u) != 0;   // !all(hist == 0)

    const int b = wave;
    float bm = -INFINITY, bd = INFINITY; int bi = 0x7fffffff;
    unsigned anz = 0;
    #pragma unroll
    for (int k = 0; k < 2; ++k) {
        const Partial Q = part[b * BPB + k * 64 + lane];
        const float m = histnz ? Q.m1 : Q.m2;
        const float d = histnz ? Q.d1 : Q.d2;
        const int   i = histnz ? Q.i1 : Q.i2;
        anz |= histnz ? (Q.flags & 2u) : (Q.flags & 4u);
        comp_upd(m, d, i, bm, bd, bi);
    }
    #pragma unroll
    for (int s = 32; s; s >>= 1) {
        const float om = __shfl_xor(bm, s);
        const float od = __shfl_xor(bd, s);
        const int   oi = __shfl_xor(bi, s);
        anz |= __shfl_xor(anz, s);
        comp_upd(om, od, oi, bm, bd, bi);
    }
    if (lane == 0) {
        const bool all_zero = (anz == 0u);            // all(masked == 0)
        const int idx = (bm > 0.0f) ? bi : 0;         // no valid pos -> argmin of all-inf = 0
        const int py = idx >> 10;
        const int px = idx & (NN - 1);
        const float lx = 2.0f * ((float)(px + 1) / 1024.0f) - 1.0f;
        const float ly = 2.0f * ((float)(py + 1) / 1024.0f) - 1.0f;
        // sm_value = sal (post cur-mask, pre-hist) at (py, px); replicate K1 arithmetic
        const float gx = grid[px * 2];
        const float gy = grid[py * 2];
        const float cx = cur[b * 2 + 0];
        const float cy = cur[b * 2 + 1];
        const float dx = gx - cx;
        const float dy = gy - cy;
        const float cd = 0.5f * (dx * dx) + 0.5f * (dy * dy);
        const float sv = sal[(size_t)b * NPIX + idx];
        const float salv = (cd <= RADIUS) ? 0.0f : sv;
        const float sm = fmaxf(salv, 0.0001f);
        const float eps = 10.0f / sm;
        out_xy[2 * b + 0] = all_zero ? 1.0f : lx;
        out_xy[2 * b + 1] = all_zero ? 1.0f : ly;
        params[4 * b + 0] = lx;                        // rbf uses raw loc, not next_xy
        params[4 * b + 1] = ly;
        params[4 * b + 2] = eps;
        params[4 * b + 3] = histnz ? 0.0f : 1.0f;      // 1 -> treat hist as ones
    }
}

// ---------------- Kernel 3: RBF mask + hist update ----------------
__global__ __launch_bounds__(256) void k_apply(
        const float* __restrict__ hist, const float* __restrict__ grid,
        const float* __restrict__ params, float* __restrict__ out_hist,
        float* __restrict__ out_mask) {
    __shared__ float r[NN];
    const int tid = threadIdx.x;
    for (int i = tid; i < NN; i += 256) r[i] = grid[i * 2];
    const int b   = blockIdx.x >> 7;
    const int blk = blockIdx.x & (BPB - 1);
    const float lx  = params[4 * b + 0];
    const float ly  = params[4 * b + 1];
    const float eps = params[4 * b + 2];
    const bool useones = params[4 * b + 3] != 0.0f;
    __syncthreads();

    float hdx2[4];
    #pragma unroll
    for (int j = 0; j < 4; ++j) {
        const float dx = r[tid * 4 + j] - lx;
        hdx2[j] = 0.5f * (dx * dx);
    }

    const size_t base = (size_t)b * NPIX + (size_t)blk * (ROWS * NN) + (size_t)tid * 4;
    #pragma unroll
    for (int it = 0; it < ROWS; ++it) {
        const float dy = r[blk * ROWS + it] - ly;
        const float hdy2 = 0.5f * (dy * dy);
        const f4 h4 = *(const f4*)(hist + base + it * NN);   // L3-hot from K1
        f4 m4, o4;
        #pragma unroll
        for (int j = 0; j < 4; ++j) {
            const float rbf = hdx2[j] + hdy2;
            const float t = rbf * eps;
            const float mk = __expf(-(t * t));
            const float hv = useones ? 1.0f : h4[j];
            float ho = hv * (1.0f - mk);
            ho = fminf(fmaxf(ho, 0.0f), 1.0f);
            m4[j] = mk;
            o4[j] = ho;
        }
        __builtin_nontemporal_store(m4, (f4*)(out_mask + base + it * NN));
        __builtin_nontemporal_store(o4, (f4*)(out_hist + base + it * NN));
    }
}

extern "C" void kernel_launch(void* const* d_in, const int* in_sizes, int n_in,
                              void* d_out, int out_size, void* d_ws, size_t ws_size,
                              hipStream_t stream) {
    const float* sal  = (const float*)d_in[0];   // (B, N, N)
    const float* hist = (const float*)d_in[1];   // (B, 1, N, N)
    const float* cur  = (const float*)d_in[2];   // (B, 2)
    const float* grid = (const float*)d_in[3];   // (N, N, 2)

    float* out      = (float*)d_out;
    float* out_xy   = out;                       // B*2
    float* out_hist = out + NB * 2;              // B*N*N
    float* out_mask = out_hist + NB * NPIX;      // B*N*N

    Partial* part = (Partial*)d_ws;              // NBLK * 32 B = 64 KiB
    float* params = (float*)((char*)d_ws + NBLK * sizeof(Partial));  // 16*4 floats

    k_reduce<<<NBLK, 256, 0, stream>>>(sal, hist, cur, grid, part);
    k_final<<<1, 1024, 0, stream>>>(part, sal, cur, grid, out_xy, params);
    k_apply<<<NBLK, 256, 0, stream>>>(hist, grid, params, out_hist, out_mask);
}